// Round 10
// baseline (121.645 us; speedup 1.0000x reference)
//
#include <hip/hip_runtime.h>
#include <hip/hip_bf16.h>

#define NNODES 131072
#define NEDGES 2097152
#define BSUB   1024
#define SSUB   128
#define FIN    300
#define FOUT   64
#define NCHUNK 256
#define CHEDGE 8192

typedef __attribute__((ext_vector_type(8))) short short8;
typedef __attribute__((ext_vector_type(8))) unsigned short ushort8;
typedef __attribute__((ext_vector_type(4))) float f32x4;

// hardware RNE f32->bf16 (compiler lowers pairs to v_cvt_pk_bf16_f32)
__device__ inline unsigned short f2bfbits(float f) {
    union { __hip_bfloat16 h; unsigned short u; } cv;
    cv.h = __float2bfloat16(f);
    return cv.u;
}
__device__ inline float bf2f(unsigned short b) {
    return __uint_as_float(((unsigned)b) << 16);
}

// ---------------------------------------------------------------------------
// Pack W [300][64] f32 into MFMA B-fragment layout (K padded to 320) AND
// zero the 1024-entry gcnt array (avoids a graph memset node).
// ---------------------------------------------------------------------------
__global__ __launch_bounds__(256) void prep_w_kernel(const float* __restrict__ W,
                                                     short* __restrict__ wfrag,
                                                     int* __restrict__ gcnt) {
    int idx = blockIdx.x * 256 + threadIdx.x;     // grid 10 x 256 = 2560
    if (idx < BSUB) gcnt[idx] = 0;
    if (idx >= 2560) return;
    int ct   = idx / 640;
    int rem  = idx % 640;
    int kt   = rem / 64;
    int lane = rem % 64;
    int col  = ct * 16 + (lane & 15);
    int kb   = kt * 32 + (lane >> 4) * 8;
#pragma unroll
    for (int e = 0; e < 8; ++e) {
        int k = kb + e;
        float v = (k < FIN) ? W[(size_t)k * FOUT + col] : 0.f;
        wfrag[(size_t)idx * 8 + e] = (short)f2bfbits(v);
    }
}

// ---------------------------------------------------------------------------
// Edge bucketing (standalone again — restores occupancy + rocprof attribution).
// Per-chunk LDS histogram (4 KB), one global atomic per nonzero bin reserves a
// range, second pass re-reads src/dst (L2-hot) and scatters packed
// (src_loc<<7 | dst_loc) u16 into fixed 4096-entry buckets.
// ---------------------------------------------------------------------------
__global__ __launch_bounds__(256) void bucket_kernel(const int* __restrict__ src,
                                                     const int* __restrict__ dst,
                                                     int* __restrict__ gcnt,
                                                     unsigned short* __restrict__ bkt) {
    __shared__ int hist[BSUB];                 // 4 KB (hist, then cursor)
    const int cb = blockIdx.x;
    const int t = threadIdx.x;
    for (int i = t; i < BSUB; i += 256) hist[i] = 0;
    __syncthreads();
    const int4* sp = (const int4*)(src + (size_t)cb * CHEDGE);
    for (int i = t; i < CHEDGE / 4; i += 256) {
        int4 v = sp[i];
        atomicAdd(&hist[v.x >> 7], 1);
        atomicAdd(&hist[v.y >> 7], 1);
        atomicAdd(&hist[v.z >> 7], 1);
        atomicAdd(&hist[v.w >> 7], 1);
    }
    __syncthreads();
    for (int i = t; i < BSUB; i += 256) {
        int c = hist[i];
        hist[i] = c ? atomicAdd(&gcnt[i], c) : 0;   // hist becomes cursor
    }
    __syncthreads();
    const int4* dp = (const int4*)(dst + (size_t)cb * CHEDGE);
    for (int i = t; i < CHEDGE / 4; i += 256) {
        int4 s4 = sp[i], d4 = dp[i];                // sp re-read is L1/L2-hot
#pragma unroll
        for (int k = 0; k < 4; ++k) {
            int s = (k == 0) ? s4.x : (k == 1) ? s4.y : (k == 2) ? s4.z : s4.w;
            int d = (k == 0) ? d4.x : (k == 1) ? d4.y : (k == 2) ? d4.z : d4.w;
            int g = s >> 7;
            int r = atomicAdd(&hist[g], 1);
            bkt[((size_t)g << 12) + r] = (unsigned short)(((s & 127) << 7) | (d & 127));
        }
    }
}

// ---------------------------------------------------------------------------
// h = in_feat @ W, bf16 MFMA 16x16x32. THE FIX: wfrag staged to LDS once per
// block — every bf16 B-fragment read was previously a global (L2-latency)
// load inside the MFMA dependency chain (327 MB of latency-exposed traffic
// across the grid; invariant pole of R5-R9 at ~90 us). Now it's ds_read_b128.
// A stays as simple in-loop global f32x4 loads (line-exact, single-use).
// ---------------------------------------------------------------------------
__global__ __launch_bounds__(256) void gemm_kernel(const float* __restrict__ x,
                                                   const short* __restrict__ wfrag,
                                                   unsigned short* __restrict__ hb) {
    __shared__ short wl[20480];                     // 40 KB: full wfrag
    __shared__ unsigned short st[4][16][FOUT];      // 8 KB: epilogue scratch

    // stage wfrag (coalesced 16B copies, 10 iters/thread)
    {
        const ushort8* srcv = (const ushort8*)wfrag;
        ushort8* dstv = (ushort8*)wl;
        for (int i = threadIdx.x; i < 2560; i += 256) dstv[i] = srcv[i];
    }
    __syncthreads();

    const int wave = threadIdx.x >> 6;
    const int lane = threadIdx.x & 63;
    const int rowbase = (blockIdx.x * 4 + wave) * 16;
    const int arow = rowbase + (lane & 15);
    const int kgrp = lane >> 4;
    const float* ap = x + (size_t)arow * FIN + kgrp * 8;

    f32x4 acc[4];
#pragma unroll
    for (int c = 0; c < 4; ++c) acc[c] = (f32x4){0.f, 0.f, 0.f, 0.f};

#pragma unroll
    for (int kt = 0; kt < 9; ++kt) {
        f32x4 lo = *(const f32x4*)(ap + kt * 32);
        f32x4 hi = *(const f32x4*)(ap + kt * 32 + 4);
        short8 afr;
        afr[0] = (short)f2bfbits(lo[0]); afr[1] = (short)f2bfbits(lo[1]);
        afr[2] = (short)f2bfbits(lo[2]); afr[3] = (short)f2bfbits(lo[3]);
        afr[4] = (short)f2bfbits(hi[0]); afr[5] = (short)f2bfbits(hi[1]);
        afr[6] = (short)f2bfbits(hi[2]); afr[7] = (short)f2bfbits(hi[3]);
#pragma unroll
        for (int ct = 0; ct < 4; ++ct) {
            short8 bfr = *(const short8*)(wl + ((ct * 10 + kt) * 64 + lane) * 8);
            acc[ct] = __builtin_amdgcn_mfma_f32_16x16x32_bf16(afr, bfr, acc[ct], 0, 0, 0);
        }
    }
    {   // K tail kt=9: k 288..319; valid k<300, invalid lanes feed zero B rows
        f32x4 t9a = (f32x4){0.f, 0.f, 0.f, 0.f};
        f32x4 t9b = (f32x4){0.f, 0.f, 0.f, 0.f};
        const float* arp = x + (size_t)arow * FIN;
        if (kgrp == 0) {
            t9a = *(const f32x4*)(arp + 288);
            t9b = *(const f32x4*)(arp + 292);
        } else if (kgrp == 1) {
            t9a = *(const f32x4*)(arp + 296);
        }
        short8 afr;
        afr[0] = (short)f2bfbits(t9a[0]); afr[1] = (short)f2bfbits(t9a[1]);
        afr[2] = (short)f2bfbits(t9a[2]); afr[3] = (short)f2bfbits(t9a[3]);
        afr[4] = (short)f2bfbits(t9b[0]); afr[5] = (short)f2bfbits(t9b[1]);
        afr[6] = (short)f2bfbits(t9b[2]); afr[7] = (short)f2bfbits(t9b[3]);
#pragma unroll
        for (int ct = 0; ct < 4; ++ct) {
            short8 bfr = *(const short8*)(wl + ((ct * 10 + 9) * 64 + lane) * 8);
            acc[ct] = __builtin_amdgcn_mfma_f32_16x16x32_bf16(afr, bfr, acc[ct], 0, 0, 0);
        }
    }

    // epilogue: wave-private LDS transpose -> 2 coalesced 16B stores
    // D layout: row = (lane>>4)*4 + r, col = ct*16 + (lane&15)
    {
        const int lrow = (lane >> 4) * 4;
        const int colb = lane & 15;
#pragma unroll
        for (int ct = 0; ct < 4; ++ct)
#pragma unroll
            for (int r = 0; r < 4; ++r)
                st[wave][lrow + r][ct * 16 + colb] = f2bfbits(acc[ct][r]);
        // wave-synchronous: this wave reads only its own st slice
        const ushort8* sv = (const ushort8*)&st[wave][0][0];   // 128 x 16B
        ushort8* hout = (ushort8*)(hb + (size_t)rowbase * FOUT);
        hout[lane] = sv[lane];
        hout[lane + 64] = sv[lane + 64];
    }
}

// ---------------------------------------------------------------------------
// Per-subgraph aggregate + norm + PReLU + pool + anchor. NO float atomics:
// edges bucketed by dst into LDS (int atomics for ranks), register accum,
// wave-owned dst rows, f32 rsqrt(deg_out) scaling via rout[].
// ---------------------------------------------------------------------------
__global__ __launch_bounds__(256) void agg_pool_kernel(const unsigned short* __restrict__ hb,
                                                       const unsigned short* __restrict__ bkt,
                                                       const int* __restrict__ gcnt,
                                                       const float* __restrict__ bias,
                                                       const float* __restrict__ prelu,
                                                       float* __restrict__ out) {
    __shared__ unsigned short hl[SSUB][FOUT];       // 16 KB bf16 bits
    __shared__ unsigned char  es[SSUB][64];         // 8 KB per-dst src lists
    __shared__ int   din[SSUB];
    __shared__ int   dout[SSUB];
    __shared__ float rout[SSUB];
    __shared__ float ps[4][FOUT];

    const int g = blockIdx.x;
    const int t = threadIdx.x;
    const int lane = t & 63;
    const int w = t >> 6;

    // load h tile (straight bf16 copy, 4 x ushort8 per thread)
    {
        const ushort8* hsrc = (const ushort8*)(hb + (size_t)g * SSUB * FOUT);
        ushort8* hdst = (ushort8*)&hl[0][0];
        for (int i = t; i < 1024; i += 256) hdst[i] = hsrc[i];
    }
    if (t < SSUB) { din[t] = 0; dout[t] = 0; }
    __syncthreads();

    const int cnt = gcnt[g];
    const unsigned short* eb = bkt + ((size_t)g << 12);

    // bucket edges by dst into LDS (int atomics only)
    for (int i = t; i < cnt; i += 256) {
        unsigned e = eb[i];
        int s = e >> 7, d = e & 127;
        int r = atomicAdd(&din[d], 1);
        es[d][r & 63] = (unsigned char)s;
        atomicAdd(&dout[s], 1);
    }
    __syncthreads();
    if (t < SSUB) rout[t] = rsqrtf((float)max(dout[t], 1));
    __syncthreads();

    // register aggregation: wave w owns dst rows w, w+4, ...
    const float bv = bias[lane];
    const float a = prelu[0];
    float pool = 0.f;
#pragma unroll 4
    for (int ii = 0; ii < 32; ++ii) {
        int d = w + 4 * ii;
        int cd = min(din[d], 64);
        float accv = 0.f;
        const unsigned* ew = (const unsigned*)&es[d][0];
        int nw = (cd + 3) >> 2;
        for (int p = 0; p < nw; ++p) {
            unsigned wd = ew[p];                        // broadcast LDS read
            int rem = cd - p * 4;
#pragma unroll
            for (int b = 0; b < 4; ++b) {
                if (b < rem) {                          // wave-uniform predicate
                    int s = (wd >> (8 * b)) & 127;
                    accv += bf2f(hl[s][lane]) * rout[s];
                }
            }
        }
        float v = accv * rsqrtf((float)max(din[d], 1)) + bv;
        v = (v > 0.f) ? v : a * v;
        if (d == SSUB - 1)
            out[(size_t)(BSUB + g) * FOUT + lane] = v;  // anchor (wave 3)
        else
            pool += v;
    }
    ps[w][lane] = pool;
    __syncthreads();
    if (w == 0) {
        float s = (ps[0][lane] + ps[1][lane]) + (ps[2][lane] + ps[3][lane]);
        out[(size_t)g * FOUT + lane] = s * (1.0f / 127.0f);
    }
}

// ---------------------------------------------------------------------------
extern "C" void kernel_launch(void* const* d_in, const int* in_sizes, int n_in,
                              void* d_out, int out_size, void* d_ws, size_t ws_size,
                              hipStream_t stream) {
    const float* in_feat = (const float*)d_in[0];
    const float* W       = (const float*)d_in[1];
    const float* bias    = (const float*)d_in[2];
    const float* prelu   = (const float*)d_in[3];
    const int*   src     = (const int*)d_in[4];
    const int*   dst     = (const int*)d_in[5];
    float* out = (float*)d_out;

    char* ws = (char*)d_ws;
    int*            gcnt  = (int*)(ws);                          // 4 KB
    short*          wfrag = (short*)(ws + 65536);                // 40 KB
    unsigned short* bkt   = (unsigned short*)(ws + (1u << 20));  // 8 MB (1024 x 4096 u16)
    unsigned short* hb    = (unsigned short*)(ws + (16u << 20)); // 16 MB bf16 h

    hipLaunchKernelGGL(prep_w_kernel,   dim3(10),        dim3(256), 0, stream, W, wfrag, gcnt);
    hipLaunchKernelGGL(bucket_kernel,   dim3(NCHUNK),    dim3(256), 0, stream, src, dst, gcnt, bkt);
    hipLaunchKernelGGL(gemm_kernel,     dim3(NNODES/64), dim3(256), 0, stream, in_feat, wfrag, hb);
    hipLaunchKernelGGL(agg_pool_kernel, dim3(BSUB),      dim3(256), 0, stream, hb, bkt, gcnt, bias, prelu, out);
}

// Round 11
// 117.314 us; speedup vs baseline: 1.0369x; 1.0369x over previous
//
#include <hip/hip_runtime.h>
#include <hip/hip_bf16.h>

#define NNODES 131072
#define NEDGES 2097152
#define BSUB   1024
#define SSUB   128
#define FIN    300
#define FOUT   64
#define NCHUNK 256
#define CHEDGE 8192

typedef __attribute__((ext_vector_type(8))) short short8;
typedef __attribute__((ext_vector_type(8))) unsigned short ushort8;
typedef __attribute__((ext_vector_type(4))) float f32x4;

// hardware RNE f32->bf16 (compiler lowers pairs to v_cvt_pk_bf16_f32)
__device__ inline unsigned short f2bfbits(float f) {
    union { __hip_bfloat16 h; unsigned short u; } cv;
    cv.h = __float2bfloat16(f);
    return cv.u;
}
__device__ inline float bf2f(unsigned short b) {
    return __uint_as_float(((unsigned)b) << 16);
}

// ---------------------------------------------------------------------------
// Pack W [300][64] f32 into MFMA B-fragment layout (K padded to 320) AND
// zero the 1024-entry gcnt array (avoids a graph memset node).
// ---------------------------------------------------------------------------
__global__ __launch_bounds__(256) void prep_w_kernel(const float* __restrict__ W,
                                                     short* __restrict__ wfrag,
                                                     int* __restrict__ gcnt) {
    int idx = blockIdx.x * 256 + threadIdx.x;     // grid 10 x 256 = 2560
    if (idx < BSUB) gcnt[idx] = 0;
    if (idx >= 2560) return;
    int ct   = idx / 640;
    int rem  = idx % 640;
    int kt   = rem / 64;
    int lane = rem % 64;
    int col  = ct * 16 + (lane & 15);
    int kb   = kt * 32 + (lane >> 4) * 8;
#pragma unroll
    for (int e = 0; e < 8; ++e) {
        int k = kb + e;
        float v = (k < FIN) ? W[(size_t)k * FOUT + col] : 0.f;
        wfrag[(size_t)idx * 8 + e] = (short)f2bfbits(v);
    }
}

// ---------------------------------------------------------------------------
// Edge bucketing. Per-chunk LDS histogram (4 KB), one global atomic per
// nonzero bin reserves a range, second pass re-reads src/dst (L2-hot) and
// scatters packed (src_loc<<7 | dst_loc) u16 into fixed 4096-entry buckets.
// ---------------------------------------------------------------------------
__global__ __launch_bounds__(256) void bucket_kernel(const int* __restrict__ src,
                                                     const int* __restrict__ dst,
                                                     int* __restrict__ gcnt,
                                                     unsigned short* __restrict__ bkt) {
    __shared__ int hist[BSUB];                 // 4 KB (hist, then cursor)
    const int cb = blockIdx.x;
    const int t = threadIdx.x;
    for (int i = t; i < BSUB; i += 256) hist[i] = 0;
    __syncthreads();
    const int4* sp = (const int4*)(src + (size_t)cb * CHEDGE);
    for (int i = t; i < CHEDGE / 4; i += 256) {
        int4 v = sp[i];
        atomicAdd(&hist[v.x >> 7], 1);
        atomicAdd(&hist[v.y >> 7], 1);
        atomicAdd(&hist[v.z >> 7], 1);
        atomicAdd(&hist[v.w >> 7], 1);
    }
    __syncthreads();
    for (int i = t; i < BSUB; i += 256) {
        int c = hist[i];
        hist[i] = c ? atomicAdd(&gcnt[i], c) : 0;   // hist becomes cursor
    }
    __syncthreads();
    const int4* dp = (const int4*)(dst + (size_t)cb * CHEDGE);
    for (int i = t; i < CHEDGE / 4; i += 256) {
        int4 s4 = sp[i], d4 = dp[i];                // sp re-read is L1/L2-hot
#pragma unroll
        for (int k = 0; k < 4; ++k) {
            int s = (k == 0) ? s4.x : (k == 1) ? s4.y : (k == 2) ? s4.z : s4.w;
            int d = (k == 0) ? d4.x : (k == 1) ? d4.y : (k == 2) ? d4.z : d4.w;
            int g = s >> 7;
            int r = atomicAdd(&hist[g], 1);
            bkt[((size_t)g << 12) + r] = (unsigned short)(((s & 127) << 7) | (d & 127));
        }
    }
}

// ---------------------------------------------------------------------------
// h = in_feat @ W, bf16 MFMA 16x16x32.
// R11 fix: __launch_bounds__(256, 2) raises the VGPR cap to ~256 (2 blocks/CU
// target) so ALL 20 A-strip f32x4 loads can be preloaded into registers and
// stay hoisted (every prior round compiled at 56-88 VGPR, pinning in-flight
// loads to ~2-3 per wave -> serial ~400-cycle round-trips = the invariant
// ~90 us). Loads are issued BEFORE the wfrag->LDS staging loop; the
// __syncthreads() is a codegen barrier that keeps them hoisted, and counted
// vmcnt drains them pipelined during the MFMA loop.
// ---------------------------------------------------------------------------
__global__ __launch_bounds__(256, 2) void gemm_kernel(const float* __restrict__ x,
                                                      const short* __restrict__ wfrag,
                                                      unsigned short* __restrict__ hb) {
    __shared__ short wl[20480];                     // 40 KB: full wfrag
    __shared__ unsigned short st[4][16][FOUT];      // 8 KB: epilogue scratch

    const int wave = threadIdx.x >> 6;
    const int lane = threadIdx.x & 63;
    const int rowbase = (blockIdx.x * 4 + wave) * 16;
    const int arow = rowbase + (lane & 15);
    const int kgrp = lane >> 4;
    const float* arp = x + (size_t)arow * FIN;
    const float* ap = arp + kgrp * 8;

    // --- preload the ENTIRE A strip: 20 f32x4, statically indexed ---
    f32x4 a[20];
#pragma unroll
    for (int kt = 0; kt < 9; ++kt) {
        a[2 * kt]     = *(const f32x4*)(ap + kt * 32);
        a[2 * kt + 1] = *(const f32x4*)(ap + kt * 32 + 4);
    }
    a[18] = (f32x4){0.f, 0.f, 0.f, 0.f};
    a[19] = (f32x4){0.f, 0.f, 0.f, 0.f};
    if (kgrp == 0) {
        a[18] = *(const f32x4*)(arp + 288);            // k 288..291
        a[19] = *(const f32x4*)(arp + 292);            // k 292..295
    } else if (kgrp == 1) {
        a[18] = *(const f32x4*)(arp + 296);            // k 296..299
    }                                                   // k>=300: zero B rows

    // --- stage wfrag to LDS (coalesced 16B copies, 10 iters/thread) ---
    {
        const ushort8* srcv = (const ushort8*)wfrag;
        ushort8* dstv = (ushort8*)wl;
        for (int i = threadIdx.x; i < 2560; i += 256) dstv[i] = srcv[i];
    }
    __syncthreads();

    f32x4 acc[4];
#pragma unroll
    for (int c = 0; c < 4; ++c) acc[c] = (f32x4){0.f, 0.f, 0.f, 0.f};

#pragma unroll
    for (int kt = 0; kt < 10; ++kt) {
        f32x4 lo = a[2 * kt];
        f32x4 hi = a[2 * kt + 1];
        short8 afr;
        afr[0] = (short)f2bfbits(lo[0]); afr[1] = (short)f2bfbits(lo[1]);
        afr[2] = (short)f2bfbits(lo[2]); afr[3] = (short)f2bfbits(lo[3]);
        afr[4] = (short)f2bfbits(hi[0]); afr[5] = (short)f2bfbits(hi[1]);
        afr[6] = (short)f2bfbits(hi[2]); afr[7] = (short)f2bfbits(hi[3]);
#pragma unroll
        for (int ct = 0; ct < 4; ++ct) {
            short8 bfr = *(const short8*)(wl + ((ct * 10 + kt) * 64 + lane) * 8);
            acc[ct] = __builtin_amdgcn_mfma_f32_16x16x32_bf16(afr, bfr, acc[ct], 0, 0, 0);
        }
    }

    // epilogue: wave-private LDS transpose -> 2 coalesced 16B stores
    // D layout: row = (lane>>4)*4 + r, col = ct*16 + (lane&15)
    {
        const int lrow = (lane >> 4) * 4;
        const int colb = lane & 15;
#pragma unroll
        for (int ct = 0; ct < 4; ++ct)
#pragma unroll
            for (int r = 0; r < 4; ++r)
                st[wave][lrow + r][ct * 16 + colb] = f2bfbits(acc[ct][r]);
        // wave-synchronous: this wave reads only its own st slice
        const ushort8* sv = (const ushort8*)&st[wave][0][0];   // 128 x 16B
        ushort8* hout = (ushort8*)(hb + (size_t)rowbase * FOUT);
        hout[lane] = sv[lane];
        hout[lane + 64] = sv[lane + 64];
    }
}

// ---------------------------------------------------------------------------
// Per-subgraph aggregate + norm + PReLU + pool + anchor. NO float atomics:
// edges bucketed by dst into LDS (int atomics for ranks), register accum,
// wave-owned dst rows, f32 rsqrt(deg_out) scaling via rout[].
// ---------------------------------------------------------------------------
__global__ __launch_bounds__(256) void agg_pool_kernel(const unsigned short* __restrict__ hb,
                                                       const unsigned short* __restrict__ bkt,
                                                       const int* __restrict__ gcnt,
                                                       const float* __restrict__ bias,
                                                       const float* __restrict__ prelu,
                                                       float* __restrict__ out) {
    __shared__ unsigned short hl[SSUB][FOUT];       // 16 KB bf16 bits
    __shared__ unsigned char  es[SSUB][64];         // 8 KB per-dst src lists
    __shared__ int   din[SSUB];
    __shared__ int   dout[SSUB];
    __shared__ float rout[SSUB];
    __shared__ float ps[4][FOUT];

    const int g = blockIdx.x;
    const int t = threadIdx.x;
    const int lane = t & 63;
    const int w = t >> 6;

    // load h tile (straight bf16 copy, 4 x ushort8 per thread)
    {
        const ushort8* hsrc = (const ushort8*)(hb + (size_t)g * SSUB * FOUT);
        ushort8* hdst = (ushort8*)&hl[0][0];
        for (int i = t; i < 1024; i += 256) hdst[i] = hsrc[i];
    }
    if (t < SSUB) { din[t] = 0; dout[t] = 0; }
    __syncthreads();

    const int cnt = gcnt[g];
    const unsigned short* eb = bkt + ((size_t)g << 12);

    // bucket edges by dst into LDS (int atomics only)
    for (int i = t; i < cnt; i += 256) {
        unsigned e = eb[i];
        int s = e >> 7, d = e & 127;
        int r = atomicAdd(&din[d], 1);
        es[d][r & 63] = (unsigned char)s;
        atomicAdd(&dout[s], 1);
    }
    __syncthreads();
    if (t < SSUB) rout[t] = rsqrtf((float)max(dout[t], 1));
    __syncthreads();

    // register aggregation: wave w owns dst rows w, w+4, ...
    const float bv = bias[lane];
    const float a = prelu[0];
    float pool = 0.f;
#pragma unroll 4
    for (int ii = 0; ii < 32; ++ii) {
        int d = w + 4 * ii;
        int cd = min(din[d], 64);
        float accv = 0.f;
        const unsigned* ew = (const unsigned*)&es[d][0];
        int nw = (cd + 3) >> 2;
        for (int p = 0; p < nw; ++p) {
            unsigned wd = ew[p];                        // broadcast LDS read
            int rem = cd - p * 4;
#pragma unroll
            for (int b = 0; b < 4; ++b) {
                if (b < rem) {                          // wave-uniform predicate
                    int s = (wd >> (8 * b)) & 127;
                    accv += bf2f(hl[s][lane]) * rout[s];
                }
            }
        }
        float v = accv * rsqrtf((float)max(din[d], 1)) + bv;
        v = (v > 0.f) ? v : a * v;
        if (d == SSUB - 1)
            out[(size_t)(BSUB + g) * FOUT + lane] = v;  // anchor (wave 3)
        else
            pool += v;
    }
    ps[w][lane] = pool;
    __syncthreads();
    if (w == 0) {
        float s = (ps[0][lane] + ps[1][lane]) + (ps[2][lane] + ps[3][lane]);
        out[(size_t)g * FOUT + lane] = s * (1.0f / 127.0f);
    }
}

// ---------------------------------------------------------------------------
extern "C" void kernel_launch(void* const* d_in, const int* in_sizes, int n_in,
                              void* d_out, int out_size, void* d_ws, size_t ws_size,
                              hipStream_t stream) {
    const float* in_feat = (const float*)d_in[0];
    const float* W       = (const float*)d_in[1];
    const float* bias    = (const float*)d_in[2];
    const float* prelu   = (const float*)d_in[3];
    const int*   src     = (const int*)d_in[4];
    const int*   dst     = (const int*)d_in[5];
    float* out = (float*)d_out;

    char* ws = (char*)d_ws;
    int*            gcnt  = (int*)(ws);                          // 4 KB
    short*          wfrag = (short*)(ws + 65536);                // 40 KB
    unsigned short* bkt   = (unsigned short*)(ws + (1u << 20));  // 8 MB (1024 x 4096 u16)
    unsigned short* hb    = (unsigned short*)(ws + (16u << 20)); // 16 MB bf16 h

    hipLaunchKernelGGL(prep_w_kernel,   dim3(10),        dim3(256), 0, stream, W, wfrag, gcnt);
    hipLaunchKernelGGL(bucket_kernel,   dim3(NCHUNK),    dim3(256), 0, stream, src, dst, gcnt, bkt);
    hipLaunchKernelGGL(gemm_kernel,     dim3(NNODES/64), dim3(256), 0, stream, in_feat, wfrag, hb);
    hipLaunchKernelGGL(agg_pool_kernel, dim3(BSUB),      dim3(256), 0, stream, hb, bkt, gcnt, bias, prelu, out);
}